// Round 2
// baseline (1199.813 us; speedup 1.0000x reference)
//
#include <hip/hip_runtime.h>

// MoE experts: N=8192, K=2, E=8, H=2048, I=1408.
// Storage dtype (fp32 vs bf16) detected at runtime by probe_k -> mode flag in ws.
// Pipeline: probe -> route -> transpose weights (to K-contiguous bf16) ->
// grouped GEMM1 (fused gate+up, SwiGLU) -> grouped GEMM2 -> weighted gather combine.

#define N_TOK 8192
#define TOPK  2
#define NEXP  8
#define HD    2048
#define ID    1408
#define NK    (N_TOK * TOPK)   // 16384

typedef __bf16 bf16x8 __attribute__((ext_vector_type(8)));
typedef float  f32x4  __attribute__((ext_vector_type(4)));

__device__ __forceinline__ float b2f(unsigned short u) {
    union { unsigned int i; float f; } v; v.i = ((unsigned int)u) << 16; return v.f;
}
__device__ __forceinline__ unsigned short f2b(float f) {
    union { float f; unsigned int i; } v; v.f = f;
    unsigned int x = v.i;
    return (unsigned short)((x + 0x7fffu + ((x >> 16) & 1u)) >> 16);   // RNE
}

// ---------------- dtype probe: 1 = fp32 storage, 0 = bf16 storage ----------------
// Low u16 of an fp32 ~N(0,1) is mantissa bits -> insane as bf16; genuine bf16 is sane.

__global__ void probe_k(const unsigned short* __restrict__ xu, int* __restrict__ mode) {
    __shared__ int c;
    if (threadIdx.x == 0) c = 0;
    __syncthreads();
    float a = fabsf(b2f(xu[threadIdx.x * 2]));
    int sane = (a > 1e-4f && a < 100.f) ? 1 : 0;
    atomicAdd(&c, sane);
    __syncthreads();
    if (threadIdx.x == 0) mode[0] = (c < 512) ? 1 : 0;
}

// ---------------- routing ----------------

__global__ void init_k(int* cnt, int* fill) {
    int t = threadIdx.x;
    if (t < NEXP) { cnt[t] = 0; fill[t] = 0; }
}

__global__ void route_count(const int* __restrict__ idx, int* __restrict__ cnt) {
    int s = blockIdx.x * 256 + threadIdx.x;
    if (s < NK) atomicAdd(&cnt[idx[s]], 1);
}

__global__ void route_scan(const int* __restrict__ cnt, int* __restrict__ base) {
    if (threadIdx.x == 0) {
        int acc = 0;
        for (int e = 0; e < NEXP; e++) { base[e] = acc; acc += cnt[e]; }
        base[NEXP] = acc;
    }
}

__global__ void route_scatter(const int* __restrict__ idx,
                              const int* __restrict__ base,
                              int* __restrict__ fill,
                              int* __restrict__ tok,
                              int* __restrict__ inv) {
    int s = blockIdx.x * 256 + threadIdx.x;
    if (s < NK) {
        int e = idx[s];
        int p = base[e] + atomicAdd(&fill[e], 1);
        tok[p] = s >> 1;           // TOPK == 2
        inv[s] = p;
    }
}

// ---------------- weight transpose: per-expert [R][C] (fp32 or bf16) -> [C][R] bf16 ----

__global__ void transpose_k(const void* __restrict__ in, unsigned short* __restrict__ out,
                            int R, int C, const int* __restrict__ mode) {
    __shared__ float tile[64][65];
    bool fp32m = (mode[0] != 0);
    int e  = blockIdx.z;
    int c0 = blockIdx.x * 64, r0 = blockIdx.y * 64;
    int t = threadIdx.x;
    if (fp32m) {
        const float* inp = (const float*)in + (size_t)e * R * C;
        for (int i = 0; i < 16; i++) {
            int lin = t + i * 256;
            int r = lin >> 6, c = lin & 63;
            tile[r][c] = inp[(size_t)(r0 + r) * C + c0 + c];
        }
    } else {
        const unsigned int* inp = (const unsigned int*)in + (size_t)e * R * (C >> 1);
        for (int i = 0; i < 8; i++) {
            int lin = t + i * 256;
            int r = lin >> 5, cu = lin & 31;
            unsigned int v = inp[(size_t)(r0 + r) * (C >> 1) + (c0 >> 1) + cu];
            tile[r][2 * cu]     = b2f((unsigned short)(v & 0xffffu));
            tile[r][2 * cu + 1] = b2f((unsigned short)(v >> 16));
        }
    }
    __syncthreads();
    unsigned int* outp = (unsigned int*)out + (size_t)e * C * (R >> 1);
    for (int i = 0; i < 8; i++) {
        int lin = t + i * 256;
        int c = lin >> 5, ru = lin & 31;
        unsigned int lo = f2b(tile[2 * ru][c]);
        unsigned int hi = f2b(tile[2 * ru + 1][c]);
        outp[(size_t)(c0 + c) * (R >> 1) + (r0 >> 1) + ru] = lo | (hi << 16);
    }
}

// ---------------- grouped GEMM1: h = x_sorted @ gate_up[e]; inter = silu(g)*u ----------

__launch_bounds__(256, 2)
__global__ void gemm1_k(const void* __restrict__ x,
                        const unsigned short* __restrict__ gupT,   // [E][2I][H] bf16
                        const int* __restrict__ base,
                        const int* __restrict__ tok,
                        unsigned short* __restrict__ inter,        // [NK][I] bf16
                        const int* __restrict__ mode) {
    int e  = blockIdx.z;
    int rt = blockIdx.y;
    int ct = blockIdx.x;
    int rbeg = base[e], rend = base[e + 1];
    int row0 = rbeg + rt * 128;
    if (row0 >= rend) return;
    bool fp32m = (mode[0] != 0);

    __shared__ unsigned short Al[8][130][8];
    __shared__ unsigned short Bg[8][130][8];
    __shared__ unsigned short Bu[8][130][8];

    int tid  = threadIdx.x;
    int lane = tid & 63;
    int wave = tid >> 6;
    int wm = wave & 1, wn = wave >> 1;
    int l15 = lane & 15, q = lane >> 4;

    const unsigned short* gptr = gupT + (size_t)e * (2 * ID) * HD + (size_t)(ct * 128) * HD;
    const unsigned short* uptr = gptr + (size_t)ID * HD;

    const char* abase[4];
    bool svalid[4];
    size_t rowbytes = fp32m ? (size_t)HD * 4 : (size_t)HD * 2;
    for (int i = 0; i < 4; i++) {
        int lin = tid + i * 256;
        int r = lin >> 3;
        int p = row0 + r;
        svalid[i] = (p < rend);
        abase[i] = svalid[i] ? ((const char*)x + (size_t)tok[p] * rowbytes) : (const char*)x;
    }

    f32x4 accg[4][4], accu[4][4];
    for (int mt = 0; mt < 4; mt++)
        for (int nt = 0; nt < 4; nt++) {
            accg[mt][nt] = (f32x4){0.f, 0.f, 0.f, 0.f};
            accu[mt][nt] = (f32x4){0.f, 0.f, 0.f, 0.f};
        }

    for (int k0 = 0; k0 < HD; k0 += 64) {
        __syncthreads();
        for (int i = 0; i < 4; i++) {
            int lin = tid + i * 256;
            int r = lin >> 3, c = lin & 7;
            uint4 av = make_uint4(0u, 0u, 0u, 0u);
            if (fp32m) {
                if (svalid[i]) {
                    const float* fp = (const float*)abase[i] + k0 + c * 8;
                    float4 f0 = *(const float4*)fp;
                    float4 f1 = *(const float4*)(fp + 4);
                    av.x = f2b(f0.x) | ((unsigned int)f2b(f0.y) << 16);
                    av.y = f2b(f0.z) | ((unsigned int)f2b(f0.w) << 16);
                    av.z = f2b(f1.x) | ((unsigned int)f2b(f1.y) << 16);
                    av.w = f2b(f1.z) | ((unsigned int)f2b(f1.w) << 16);
                }
            } else {
                if (svalid[i])
                    av = *(const uint4*)((const unsigned short*)abase[i] + k0 + c * 8);
            }
            *(uint4*)&Al[c][r][0] = av;
            *(uint4*)&Bg[c][r][0] = *(const uint4*)(gptr + (size_t)r * HD + k0 + c * 8);
            *(uint4*)&Bu[c][r][0] = *(const uint4*)(uptr + (size_t)r * HD + k0 + c * 8);
        }
        __syncthreads();
        for (int ks = 0; ks < 2; ks++) {
            int kc = ks * 4 + q;
            bf16x8 af[4], bg[4], bu[4];
            for (int mt = 0; mt < 4; mt++)
                af[mt] = *(bf16x8*)&Al[kc][wm * 64 + mt * 16 + l15][0];
            for (int nt = 0; nt < 4; nt++) {
                bg[nt] = *(bf16x8*)&Bg[kc][wn * 64 + nt * 16 + l15][0];
                bu[nt] = *(bf16x8*)&Bu[kc][wn * 64 + nt * 16 + l15][0];
            }
            for (int mt = 0; mt < 4; mt++)
                for (int nt = 0; nt < 4; nt++) {
                    accg[mt][nt] = __builtin_amdgcn_mfma_f32_16x16x32_bf16(af[mt], bg[nt], accg[mt][nt], 0, 0, 0);
                    accu[mt][nt] = __builtin_amdgcn_mfma_f32_16x16x32_bf16(af[mt], bu[nt], accu[mt][nt], 0, 0, 0);
                }
        }
    }

    for (int mt = 0; mt < 4; mt++) {
        int rb = wm * 64 + mt * 16 + q * 4;
        for (int reg = 0; reg < 4; reg++) {
            int p = row0 + rb + reg;
            if (p >= rend) continue;
            for (int nt = 0; nt < 4; nt++) {
                int col = ct * 128 + wn * 64 + nt * 16 + l15;
                float g = accg[mt][nt][reg];
                float u = accu[mt][nt][reg];
                float s = g / (1.f + __expf(-g));
                inter[(size_t)p * ID + col] = f2b(s * u);
            }
        }
    }
}

// ---------------- grouped GEMM2: out_sorted = inter @ down[e] ----------

__launch_bounds__(256, 2)
__global__ void gemm2_k(const unsigned short* __restrict__ inter,  // [NK][I] bf16
                        const unsigned short* __restrict__ dwnT,   // [E][H][I] bf16
                        const int* __restrict__ base,
                        unsigned short* __restrict__ outs) {       // [NK][H] bf16
    int e  = blockIdx.z;
    int rt = blockIdx.y;
    int ct = blockIdx.x;
    int rbeg = base[e], rend = base[e + 1];
    int row0 = rbeg + rt * 128;
    if (row0 >= rend) return;

    __shared__ unsigned short Al[8][130][8];
    __shared__ unsigned short Bl[8][130][8];

    int tid  = threadIdx.x;
    int lane = tid & 63;
    int wave = tid >> 6;
    int wm = wave & 1, wn = wave >> 1;
    int l15 = lane & 15, q = lane >> 4;

    const unsigned short* bptr = dwnT + (size_t)e * HD * ID + (size_t)(ct * 128) * ID;

    bool svalid[4];
    int  srow[4];
    for (int i = 0; i < 4; i++) {
        int lin = tid + i * 256;
        int r = lin >> 3;
        srow[i] = row0 + r;
        svalid[i] = (srow[i] < rend);
    }

    f32x4 acc[4][4];
    for (int mt = 0; mt < 4; mt++)
        for (int nt = 0; nt < 4; nt++) acc[mt][nt] = (f32x4){0.f, 0.f, 0.f, 0.f};

    for (int k0 = 0; k0 < ID; k0 += 64) {
        __syncthreads();
        for (int i = 0; i < 4; i++) {
            int lin = tid + i * 256;
            int r = lin >> 3, c = lin & 7;
            uint4 av = make_uint4(0u, 0u, 0u, 0u);
            if (svalid[i]) av = *(const uint4*)(inter + (size_t)srow[i] * ID + k0 + c * 8);
            *(uint4*)&Al[c][r][0] = av;
            *(uint4*)&Bl[c][r][0] = *(const uint4*)(bptr + (size_t)r * ID + k0 + c * 8);
        }
        __syncthreads();
        for (int ks = 0; ks < 2; ks++) {
            int kc = ks * 4 + q;
            bf16x8 af[4], bf[4];
            for (int mt = 0; mt < 4; mt++)
                af[mt] = *(bf16x8*)&Al[kc][wm * 64 + mt * 16 + l15][0];
            for (int nt = 0; nt < 4; nt++)
                bf[nt] = *(bf16x8*)&Bl[kc][wn * 64 + nt * 16 + l15][0];
            for (int mt = 0; mt < 4; mt++)
                for (int nt = 0; nt < 4; nt++)
                    acc[mt][nt] = __builtin_amdgcn_mfma_f32_16x16x32_bf16(af[mt], bf[nt], acc[mt][nt], 0, 0, 0);
        }
    }

    for (int mt = 0; mt < 4; mt++) {
        int rb = wm * 64 + mt * 16 + q * 4;
        for (int reg = 0; reg < 4; reg++) {
            int p = row0 + rb + reg;
            if (p >= rend) continue;
            for (int nt = 0; nt < 4; nt++) {
                int col = ct * 128 + wn * 64 + nt * 16 + l15;
                outs[(size_t)p * HD + col] = f2b(acc[mt][nt][reg]);
            }
        }
    }
}

// ---------------- weighted gather combine ----------------

__global__ void combine_k(const unsigned short* __restrict__ outs,  // [NK][H] bf16
                          const int* __restrict__ inv,              // [NK]
                          const void* __restrict__ w,               // [N][K]
                          void* __restrict__ out,                   // [N][H]
                          const int* __restrict__ mode) {
    bool fp32m = (mode[0] != 0);
    int gid = blockIdx.x * 256 + threadIdx.x;   // N*H/8 threads
    int t  = gid >> 8;                          // H/8 = 256 chunks per token
    int c8 = (gid & 255) * 8;
    int p0 = inv[t * 2], p1 = inv[t * 2 + 1];
    float w0, w1;
    if (fp32m) {
        const float* wf = (const float*)w;
        w0 = wf[t * 2]; w1 = wf[t * 2 + 1];
    } else {
        const unsigned short* wu = (const unsigned short*)w;
        w0 = b2f(wu[t * 2]); w1 = b2f(wu[t * 2 + 1]);
    }
    uint4 v0 = *(const uint4*)(outs + (size_t)p0 * HD + c8);
    uint4 v1 = *(const uint4*)(outs + (size_t)p1 * HD + c8);
    const unsigned short* a = (const unsigned short*)&v0;
    const unsigned short* b = (const unsigned short*)&v1;
    float r[8];
    for (int i = 0; i < 8; i++) r[i] = w0 * b2f(a[i]) + w1 * b2f(b[i]);
    if (fp32m) {
        float* of = (float*)out + (size_t)t * HD + c8;
        float4 o0 = make_float4(r[0], r[1], r[2], r[3]);
        float4 o1 = make_float4(r[4], r[5], r[6], r[7]);
        *(float4*)of = o0;
        *(float4*)(of + 4) = o1;
    } else {
        uint4 o;
        unsigned int* ro = (unsigned int*)&o;
        for (int i = 0; i < 4; i++)
            ro[i] = f2b(r[2 * i]) | ((unsigned int)f2b(r[2 * i + 1]) << 16);
        *(uint4*)((unsigned short*)out + (size_t)t * HD + c8) = o;
    }
}

// ---------------- launch ----------------

extern "C" void kernel_launch(void* const* d_in, const int* in_sizes, int n_in,
                              void* d_out, int out_size, void* d_ws, size_t ws_size,
                              hipStream_t stream) {
    const void* x   = d_in[0];                 // [N][H] fp32 or bf16
    const int*  idx = (const int*)d_in[1];     // [N][K] i32
    const void* w   = d_in[2];                 // [N][K] fp32 or bf16
    const void* gup = d_in[3];                 // [E][H][2I]
    const void* dwn = d_in[4];                 // [E][I][H]

    char* ws = (char*)d_ws;
    int* mode = (int*)(ws);              // 1 int
    int* cnt  = (int*)(ws + 64);         // 8 ints
    int* base = (int*)(ws + 128);        // 9 ints
    int* fill = (int*)(ws + 192);        // 8 ints
    int* tok  = (int*)(ws + 256);        // NK ints
    int* inv  = (int*)(ws + 256 + 4 * NK);
    unsigned short* inter = (unsigned short*)(ws + 262144);          // [NK][I]  bf16
    unsigned short* outs  = inter + (size_t)NK * ID;                 // [NK][H]  bf16
    unsigned short* gupT  = outs  + (size_t)NK * HD;                 // [E][2I][H] bf16
    unsigned short* dwnT  = gupT  + (size_t)NEXP * 2 * ID * HD;      // [E][H][I]  bf16
    // total ws use ~252 MB

    probe_k<<<1, 1024, 0, stream>>>((const unsigned short*)x, mode);

    init_k<<<1, 64, 0, stream>>>(cnt, fill);
    route_count<<<NK / 256, 256, 0, stream>>>(idx, cnt);
    route_scan<<<1, 64, 0, stream>>>(cnt, base);
    route_scatter<<<NK / 256, 256, 0, stream>>>(idx, base, fill, tok, inv);

    transpose_k<<<dim3(2 * ID / 64, HD / 64, NEXP), 256, 0, stream>>>(
        gup, gupT, HD, 2 * ID, mode);
    transpose_k<<<dim3(HD / 64, ID / 64, NEXP), 256, 0, stream>>>(
        dwn, dwnT, ID, HD, mode);

    gemm1_k<<<dim3(ID / 128, 128, NEXP), 256, 0, stream>>>(x, gupT, base, tok, inter, mode);
    gemm2_k<<<dim3(HD / 128, 128, NEXP), 256, 0, stream>>>(inter, dwnT, base, outs);

    combine_k<<<(N_TOK * HD / 8) / 256, 256, 0, stream>>>(outs, inv, w, d_out, mode);
}

// Round 3
// 1082.302 us; speedup vs baseline: 1.1086x; 1.1086x over previous
//
#include <hip/hip_runtime.h>

// MoE experts: N=8192, K=2, E=8, H=2048, I=1408.
// Round 3: global_load_lds (width=16) DMA staging with XOR-swizzled LDS layout
// (conflict-free b128 fragment reads), x pre-converted to bf16, gemm2 at 3 blocks/CU.

#define N_TOK 8192
#define TOPK  2
#define NEXP  8
#define HD    2048
#define ID    1408
#define NK    (N_TOK * TOPK)   // 16384

typedef __bf16 bf16x8 __attribute__((ext_vector_type(8)));
typedef float  f32x4  __attribute__((ext_vector_type(4)));

__device__ __forceinline__ float b2f(unsigned short u) {
    union { unsigned int i; float f; } v; v.i = ((unsigned int)u) << 16; return v.f;
}
__device__ __forceinline__ unsigned short f2b(float f) {
    union { float f; unsigned int i; } v; v.f = f;
    unsigned int x = v.i;
    return (unsigned short)((x + 0x7fffu + ((x >> 16) & 1u)) >> 16);   // RNE
}

// async global->LDS, 16B per lane; dest = wave-uniform base + lane*16
__device__ __forceinline__ void glds16(const void* g, void* l) {
    __builtin_amdgcn_global_load_lds(
        (const __attribute__((address_space(1))) unsigned int*)g,
        (__attribute__((address_space(3))) unsigned int*)l,
        16, 0, 0);
}

// ---------------- dtype probe: 1 = fp32 storage, 0 = bf16 storage ----------------

__global__ void probe_k(const unsigned short* __restrict__ xu, int* __restrict__ mode) {
    __shared__ int c;
    if (threadIdx.x == 0) c = 0;
    __syncthreads();
    float a = fabsf(b2f(xu[threadIdx.x * 2]));
    int sane = (a > 1e-4f && a < 100.f) ? 1 : 0;
    atomicAdd(&c, sane);
    __syncthreads();
    if (threadIdx.x == 0) mode[0] = (c < 512) ? 1 : 0;
}

// ---------------- x -> bf16 ----------------

__global__ void convert_x(const void* __restrict__ x, unsigned short* __restrict__ xb,
                          const int* __restrict__ mode) {
    int gid = blockIdx.x * 256 + threadIdx.x;      // N*H/8 threads
    size_t o = (size_t)gid * 8;
    if (mode[0]) {
        const float* f = (const float*)x + o;
        float4 f0 = *(const float4*)f;
        float4 f1 = *(const float4*)(f + 4);
        uint4 v;
        v.x = f2b(f0.x) | ((unsigned int)f2b(f0.y) << 16);
        v.y = f2b(f0.z) | ((unsigned int)f2b(f0.w) << 16);
        v.z = f2b(f1.x) | ((unsigned int)f2b(f1.y) << 16);
        v.w = f2b(f1.z) | ((unsigned int)f2b(f1.w) << 16);
        *(uint4*)(xb + o) = v;
    } else {
        *(uint4*)(xb + o) = *(const uint4*)((const unsigned short*)x + o);
    }
}

// ---------------- routing ----------------

__global__ void init_k(int* cnt, int* fill) {
    int t = threadIdx.x;
    if (t < NEXP) { cnt[t] = 0; fill[t] = 0; }
}

__global__ void route_count(const int* __restrict__ idx, int* __restrict__ cnt) {
    int s = blockIdx.x * 256 + threadIdx.x;
    if (s < NK) atomicAdd(&cnt[idx[s]], 1);
}

__global__ void route_scan(const int* __restrict__ cnt, int* __restrict__ base) {
    if (threadIdx.x == 0) {
        int acc = 0;
        for (int e = 0; e < NEXP; e++) { base[e] = acc; acc += cnt[e]; }
        base[NEXP] = acc;
    }
}

__global__ void route_scatter(const int* __restrict__ idx,
                              const int* __restrict__ base,
                              int* __restrict__ fill,
                              int* __restrict__ tok,
                              int* __restrict__ inv) {
    int s = blockIdx.x * 256 + threadIdx.x;
    if (s < NK) {
        int e = idx[s];
        int p = base[e] + atomicAdd(&fill[e], 1);
        tok[p] = s >> 1;           // TOPK == 2
        inv[s] = p;
    }
}

// ---------------- weight transpose: per-expert [R][C] (fp32 or bf16) -> [C][R] bf16 ----

__global__ void transpose_k(const void* __restrict__ in, unsigned short* __restrict__ out,
                            int R, int C, const int* __restrict__ mode) {
    __shared__ float tile[64][65];
    bool fp32m = (mode[0] != 0);
    int e  = blockIdx.z;
    int c0 = blockIdx.x * 64, r0 = blockIdx.y * 64;
    int t = threadIdx.x;
    if (fp32m) {
        const float* inp = (const float*)in + (size_t)e * R * C;
        for (int i = 0; i < 16; i++) {
            int lin = t + i * 256;
            int r = lin >> 6, c = lin & 63;
            tile[r][c] = inp[(size_t)(r0 + r) * C + c0 + c];
        }
    } else {
        const unsigned int* inp = (const unsigned int*)in + (size_t)e * R * (C >> 1);
        for (int i = 0; i < 8; i++) {
            int lin = t + i * 256;
            int r = lin >> 5, cu = lin & 31;
            unsigned int v = inp[(size_t)(r0 + r) * (C >> 1) + (c0 >> 1) + cu];
            tile[r][2 * cu]     = b2f((unsigned short)(v & 0xffffu));
            tile[r][2 * cu + 1] = b2f((unsigned short)(v >> 16));
        }
    }
    __syncthreads();
    unsigned int* outp = (unsigned int*)out + (size_t)e * C * (R >> 1);
    for (int i = 0; i < 8; i++) {
        int lin = t + i * 256;
        int c = lin >> 5, ru = lin & 31;
        unsigned int lo = f2b(tile[2 * ru][c]);
        unsigned int hi = f2b(tile[2 * ru + 1][c]);
        outp[(size_t)(c0 + c) * (R >> 1) + (r0 >> 1) + ru] = lo | (hi << 16);
    }
}

// LDS swizzle: element (row r, k-chunk c8) lives at 16B-slot  r*8 + (c8 ^ (r&7)).
// - DMA write: wave writes slots [wbase, wbase+64) contiguously (bank-sequential).
// - Frag read b128: 16 consecutive rows x fixed kc per quad -> every quad covers
//   all 32 banks exactly twice = structural minimum, zero conflicts.

// ---------------- grouped GEMM1: h = x_sorted @ gate_up[e]; inter = silu(g)*u ----------

__launch_bounds__(256, 2)
__global__ void gemm1_k(const unsigned short* __restrict__ xb,     // [N][H] bf16
                        const unsigned short* __restrict__ gupT,   // [E][2I][H] bf16
                        const int* __restrict__ base,
                        const int* __restrict__ tok,
                        unsigned short* __restrict__ inter) {      // [NK][I] bf16
    int e  = blockIdx.z;
    int rt = blockIdx.x;
    int ct = blockIdx.y;
    int rbeg = base[e], rend = base[e + 1];
    int row0 = rbeg + rt * 128;
    if (row0 >= rend) return;

    __shared__ unsigned short As[128 * 64];
    __shared__ unsigned short Bgs[128 * 64];
    __shared__ unsigned short Bus[128 * 64];

    int tid  = threadIdx.x;
    int lane = tid & 63;
    int wave = tid >> 6;
    int wm = wave & 1, wn = wave >> 1;
    int l15 = lane & 15, q = lane >> 4;

    const unsigned short* gptr = gupT + (size_t)e * (2 * ID) * HD + (size_t)(ct * 128) * HD;
    const unsigned short* uptr = gptr + (size_t)ID * HD;

    // staging descriptors: round i covers slots [i*256, i*256+256)
    const unsigned short* agp[4];
    int boff[4];
    int wslot[4];
    for (int i = 0; i < 4; i++) {
        int s = i * 256 + wave * 64 + lane;   // this lane's slot
        int r = s >> 3;
        int c = (s & 7) ^ (r & 7);
        int p = row0 + r;
        bool sv = (p < rend);
        agp[i]  = (sv ? xb + (size_t)tok[p] * HD : xb) + c * 8;
        boff[i] = r * HD + c * 8;
        wslot[i] = (i * 256 + wave * 64) * 8;  // wave-uniform LDS base (in shorts)
    }

    // fragment read keys
    int arow[4], brow[4];
    for (int mt = 0; mt < 4; mt++) arow[mt] = wm * 64 + mt * 16 + l15;
    for (int nt = 0; nt < 4; nt++) brow[nt] = wn * 64 + nt * 16 + l15;

    f32x4 accg[4][4], accu[4][4];
    for (int mt = 0; mt < 4; mt++)
        for (int nt = 0; nt < 4; nt++) {
            accg[mt][nt] = (f32x4){0.f, 0.f, 0.f, 0.f};
            accu[mt][nt] = (f32x4){0.f, 0.f, 0.f, 0.f};
        }

    for (int k0 = 0; k0 < HD; k0 += 64) {
        __syncthreads();
        for (int i = 0; i < 4; i++) {
            glds16(agp[i] + k0,         &As[wslot[i]]);
            glds16(gptr + boff[i] + k0, &Bgs[wslot[i]]);
            glds16(uptr + boff[i] + k0, &Bus[wslot[i]]);
        }
        __syncthreads();
        for (int ks = 0; ks < 2; ks++) {
            int kc = ks * 4 + q;
            bf16x8 af[4], bg[4], bu[4];
            for (int mt = 0; mt < 4; mt++)
                af[mt] = *(bf16x8*)&As[(arow[mt] * 8 + (kc ^ (arow[mt] & 7))) * 8];
            for (int nt = 0; nt < 4; nt++) {
                bg[nt] = *(bf16x8*)&Bgs[(brow[nt] * 8 + (kc ^ (brow[nt] & 7))) * 8];
                bu[nt] = *(bf16x8*)&Bus[(brow[nt] * 8 + (kc ^ (brow[nt] & 7))) * 8];
            }
            for (int mt = 0; mt < 4; mt++)
                for (int nt = 0; nt < 4; nt++) {
                    accg[mt][nt] = __builtin_amdgcn_mfma_f32_16x16x32_bf16(af[mt], bg[nt], accg[mt][nt], 0, 0, 0);
                    accu[mt][nt] = __builtin_amdgcn_mfma_f32_16x16x32_bf16(af[mt], bu[nt], accu[mt][nt], 0, 0, 0);
                }
        }
    }

    for (int mt = 0; mt < 4; mt++) {
        int rb = wm * 64 + mt * 16 + q * 4;
        for (int reg = 0; reg < 4; reg++) {
            int p = row0 + rb + reg;
            if (p >= rend) continue;
            for (int nt = 0; nt < 4; nt++) {
                int col = ct * 128 + wn * 64 + nt * 16 + l15;
                float g = accg[mt][nt][reg];
                float u = accu[mt][nt][reg];
                float s = g / (1.f + __expf(-g));
                inter[(size_t)p * ID + col] = f2b(s * u);
            }
        }
    }
}

// ---------------- grouped GEMM2: out_sorted = inter @ down[e] ----------

__launch_bounds__(256, 3)
__global__ void gemm2_k(const unsigned short* __restrict__ inter,  // [NK][I] bf16
                        const unsigned short* __restrict__ dwnT,   // [E][H][I] bf16
                        const int* __restrict__ base,
                        unsigned short* __restrict__ outs) {       // [NK][H] bf16
    int e  = blockIdx.z;
    int rt = blockIdx.x;
    int ct = blockIdx.y;
    int rbeg = base[e], rend = base[e + 1];
    int row0 = rbeg + rt * 128;
    if (row0 >= rend) return;

    __shared__ unsigned short As[128 * 64];
    __shared__ unsigned short Bs[128 * 64];

    int tid  = threadIdx.x;
    int lane = tid & 63;
    int wave = tid >> 6;
    int wm = wave & 1, wn = wave >> 1;
    int l15 = lane & 15, q = lane >> 4;

    const unsigned short* bptr = dwnT + (size_t)e * HD * ID + (size_t)(ct * 128) * ID;

    const unsigned short* agp[4];
    int boff[4];
    int wslot[4];
    for (int i = 0; i < 4; i++) {
        int s = i * 256 + wave * 64 + lane;
        int r = s >> 3;
        int c = (s & 7) ^ (r & 7);
        int p = row0 + r;
        bool sv = (p < rend);
        agp[i]  = (sv ? inter + (size_t)p * ID : inter) + c * 8;
        boff[i] = r * ID + c * 8;
        wslot[i] = (i * 256 + wave * 64) * 8;
    }

    int arow[4], brow[4];
    for (int mt = 0; mt < 4; mt++) arow[mt] = wm * 64 + mt * 16 + l15;
    for (int nt = 0; nt < 4; nt++) brow[nt] = wn * 64 + nt * 16 + l15;

    f32x4 acc[4][4];
    for (int mt = 0; mt < 4; mt++)
        for (int nt = 0; nt < 4; nt++) acc[mt][nt] = (f32x4){0.f, 0.f, 0.f, 0.f};

    for (int k0 = 0; k0 < ID; k0 += 64) {
        __syncthreads();
        for (int i = 0; i < 4; i++) {
            glds16(agp[i] + k0,         &As[wslot[i]]);
            glds16(bptr + boff[i] + k0, &Bs[wslot[i]]);
        }
        __syncthreads();
        for (int ks = 0; ks < 2; ks++) {
            int kc = ks * 4 + q;
            bf16x8 af[4], bf[4];
            for (int mt = 0; mt < 4; mt++)
                af[mt] = *(bf16x8*)&As[(arow[mt] * 8 + (kc ^ (arow[mt] & 7))) * 8];
            for (int nt = 0; nt < 4; nt++)
                bf[nt] = *(bf16x8*)&Bs[(brow[nt] * 8 + (kc ^ (brow[nt] & 7))) * 8];
            for (int mt = 0; mt < 4; mt++)
                for (int nt = 0; nt < 4; nt++)
                    acc[mt][nt] = __builtin_amdgcn_mfma_f32_16x16x32_bf16(af[mt], bf[nt], acc[mt][nt], 0, 0, 0);
        }
    }

    for (int mt = 0; mt < 4; mt++) {
        int rb = wm * 64 + mt * 16 + q * 4;
        for (int reg = 0; reg < 4; reg++) {
            int p = row0 + rb + reg;
            if (p >= rend) continue;
            for (int nt = 0; nt < 4; nt++) {
                int col = ct * 128 + wn * 64 + nt * 16 + l15;
                outs[(size_t)p * HD + col] = f2b(acc[mt][nt][reg]);
            }
        }
    }
}

// ---------------- weighted gather combine ----------------

__global__ void combine_k(const unsigned short* __restrict__ outs,  // [NK][H] bf16
                          const int* __restrict__ inv,              // [NK]
                          const void* __restrict__ w,               // [N][K]
                          void* __restrict__ out,                   // [N][H]
                          const int* __restrict__ mode) {
    bool fp32m = (mode[0] != 0);
    int gid = blockIdx.x * 256 + threadIdx.x;   // N*H/8 threads
    int t  = gid >> 8;                          // H/8 = 256 chunks per token
    int c8 = (gid & 255) * 8;
    int p0 = inv[t * 2], p1 = inv[t * 2 + 1];
    float w0, w1;
    if (fp32m) {
        const float* wf = (const float*)w;
        w0 = wf[t * 2]; w1 = wf[t * 2 + 1];
    } else {
        const unsigned short* wu = (const unsigned short*)w;
        w0 = b2f(wu[t * 2]); w1 = b2f(wu[t * 2 + 1]);
    }
    uint4 v0 = *(const uint4*)(outs + (size_t)p0 * HD + c8);
    uint4 v1 = *(const uint4*)(outs + (size_t)p1 * HD + c8);
    const unsigned short* a = (const unsigned short*)&v0;
    const unsigned short* b = (const unsigned short*)&v1;
    float r[8];
    for (int i = 0; i < 8; i++) r[i] = w0 * b2f(a[i]) + w1 * b2f(b[i]);
    if (fp32m) {
        float* of = (float*)out + (size_t)t * HD + c8;
        *(float4*)of       = make_float4(r[0], r[1], r[2], r[3]);
        *(float4*)(of + 4) = make_float4(r[4], r[5], r[6], r[7]);
    } else {
        uint4 o;
        unsigned int* ro = (unsigned int*)&o;
        for (int i = 0; i < 4; i++)
            ro[i] = f2b(r[2 * i]) | ((unsigned int)f2b(r[2 * i + 1]) << 16);
        *(uint4*)((unsigned short*)out + (size_t)t * HD + c8) = o;
    }
}

// ---------------- launch ----------------

extern "C" void kernel_launch(void* const* d_in, const int* in_sizes, int n_in,
                              void* d_out, int out_size, void* d_ws, size_t ws_size,
                              hipStream_t stream) {
    const void* x   = d_in[0];                 // [N][H] fp32 or bf16
    const int*  idx = (const int*)d_in[1];     // [N][K] i32
    const void* w   = d_in[2];                 // [N][K] fp32 or bf16
    const void* gup = d_in[3];                 // [E][H][2I]
    const void* dwn = d_in[4];                 // [E][I][H]

    char* ws = (char*)d_ws;
    int* mode = (int*)(ws);
    int* cnt  = (int*)(ws + 64);
    int* base = (int*)(ws + 128);
    int* fill = (int*)(ws + 192);
    int* tok  = (int*)(ws + 256);
    int* inv  = (int*)(ws + 256 + 4 * NK);
    unsigned short* inter = (unsigned short*)(ws + 262144);          // [NK][I]  bf16
    unsigned short* outs  = inter + (size_t)NK * ID;                 // [NK][H]  bf16
    unsigned short* gupT  = outs  + (size_t)NK * HD;                 // [E][2I][H] bf16
    unsigned short* dwnT  = gupT  + (size_t)NEXP * 2 * ID * HD;      // [E][H][I]  bf16
    unsigned short* xb    = dwnT  + (size_t)NEXP * HD * ID;          // [N][H]  bf16
    // total ws use ~286 MB

    probe_k<<<1, 1024, 0, stream>>>((const unsigned short*)x, mode);
    convert_x<<<(N_TOK * HD / 8) / 256, 256, 0, stream>>>(x, xb, mode);

    init_k<<<1, 64, 0, stream>>>(cnt, fill);
    route_count<<<NK / 256, 256, 0, stream>>>(idx, cnt);
    route_scan<<<1, 64, 0, stream>>>(cnt, base);
    route_scatter<<<NK / 256, 256, 0, stream>>>(idx, base, fill, tok, inv);

    transpose_k<<<dim3(2 * ID / 64, HD / 64, NEXP), 256, 0, stream>>>(
        gup, gupT, HD, 2 * ID, mode);
    transpose_k<<<dim3(HD / 64, ID / 64, NEXP), 256, 0, stream>>>(
        dwn, dwnT, ID, HD, mode);

    gemm1_k<<<dim3(128, ID / 128, NEXP), 256, 0, stream>>>(xb, gupT, base, tok, inter);
    gemm2_k<<<dim3(128, HD / 128, NEXP), 256, 0, stream>>>(inter, dwnT, base, outs);

    combine_k<<<(N_TOK * HD / 8) / 256, 256, 0, stream>>>(outs, inv, w, d_out, mode);
}